// Round 12
// baseline (62.565 us; speedup 1.0000x reference)
//
#include <hip/hip_runtime.h>
#include <hip/hip_bf16.h>
#include <stdint.h>

// Problem constants
#define B_DIM 8
#define T_DIM 2048
#define INNER 256      // IN_DIM == HEAD_TOTAL == 256
#define NEGV (-1e9f)
#define SCALE 0.0625f  // 1/sqrt(256)

typedef __bf16 bf16_t;
typedef __bf16 bf16x8 __attribute__((ext_vector_type(8)));
typedef float f32x4 __attribute__((ext_vector_type(4)));

// ---- async global->LDS, 16B per lane (global_load_lds_dwordx4) ----
__device__ inline void gload_lds16(const bf16_t* g, bf16_t* lds) {
  __builtin_amdgcn_global_load_lds(
      (__attribute__((address_space(1))) void*)(g),
      (__attribute__((address_space(3))) void*)(lds),
      16, 0, 0);
}

// Stage a 128x64 bf16 tile (row stride ldg elements) into lds[128][64].
// Linear LDS layout; wave-uniform LDS base + lane*16 (HW requirement).
__device__ inline void stage_tile(const bf16_t* gbase, int ldg,
                                  bf16_t (*lds)[64], int tid) {
  const int l = tid & 63;
  const int w = tid >> 6;
  const int sub = l >> 3;        // row within 8-row chunk
  const int ce = (l & 7) * 8;    // starting column element (8 bf16 = 16B)
#pragma unroll
  for (int i = 0; i < 4; ++i) {
    const int chunk = i * 4 + w;               // 0..15, uniform per wave
    const int row = chunk * 8 + sub;
    gload_lds16(gbase + (size_t)row * ldg + ce, &lds[chunk * 8][0]);
  }
}

// Stage a 128x64 tile from FP32 global into bf16 LDS (reg-staged convert),
// 256 threads. Issue all 8 global loads first, then cvt + ds_write.
__device__ inline void stage_tile_cvt(const float* gbase, int ldg,
                                      bf16_t (*lds)[64], int tid) {
  const int l = tid & 63;
  const int w = tid >> 6;
  const int sub = l >> 3;
  const int ce = (l & 7) * 8;
  f32x4 v[4][2];
#pragma unroll
  for (int i = 0; i < 4; ++i) {
    const int row = (i * 4 + w) * 8 + sub;
    const float* p = gbase + (size_t)row * ldg + ce;
    v[i][0] = *(const f32x4*)p;
    v[i][1] = *(const f32x4*)(p + 4);
  }
#pragma unroll
  for (int i = 0; i < 4; ++i) {
    const int row = (i * 4 + w) * 8 + sub;
    bf16x8 o;
#pragma unroll
    for (int j = 0; j < 4; ++j) {
      o[j]     = (bf16_t)v[i][0][j];
      o[4 + j] = (bf16_t)v[i][1][j];
    }
    *(bf16x8*)&lds[row][ce] = o;
  }
}

// ---- Kernel 0: BT[j][i] = sum_o Wq[o][i] * Wk[o][j]  (= M^T, bf16) ----
// e = x Wq^T Wk x^T = (x M) x^T with M = Wq^T Wk. BT is M stored [j][i] so
// the downstream GEMM (C = A B^T, operands [row][k]) consumes it directly.
// Block j: Wk[o][j] is block-uniform (s_load); Wq row reads coalesced 1KB;
// output row BT[j][:] coalesced.
__global__ __launch_bounds__(256) void m_kernel(
    const float* __restrict__ Wq, const float* __restrict__ Wk,
    bf16_t* __restrict__ BT) {
  const int j = blockIdx.x;    // 0..255
  const int i = threadIdx.x;   // 0..255
  float a0 = 0.f, a1 = 0.f, a2 = 0.f, a3 = 0.f;
#pragma unroll 8
  for (int o = 0; o < INNER; o += 4) {
    const float k0 = Wk[(size_t)(o + 0) * INNER + j];
    const float k1 = Wk[(size_t)(o + 1) * INNER + j];
    const float k2 = Wk[(size_t)(o + 2) * INNER + j];
    const float k3 = Wk[(size_t)(o + 3) * INNER + j];
    a0 += Wq[(size_t)(o + 0) * INNER + i] * k0;
    a1 += Wq[(size_t)(o + 1) * INNER + i] * k1;
    a2 += Wq[(size_t)(o + 2) * INNER + i] * k2;
    a3 += Wq[(size_t)(o + 3) * INNER + i] * k3;
  }
  BT[(size_t)j * INNER + i] = (bf16_t)((a0 + a1) + (a2 + a3));
}

// ---- Kernel 1: Y = x @ M  (A = x fp32 cvt-staged, B = BT bf16) ----
// Single projection (was two: Q and K). m97 single-buffered structure.
__global__ __launch_bounds__(256) void y_kernel(
    const float* __restrict__ x, const bf16_t* __restrict__ BT,
    bf16_t* __restrict__ Y) {
  __shared__ bf16_t Al[128][64];
  __shared__ bf16_t Bl[128][64];
  const int tid = threadIdx.x;
  const int mrow = blockIdx.x * 128;   // row in [0, B*T)
  const int ncol = blockIdx.y * 128;   // out-feature j

  const int l = tid & 63, wid = tid >> 6, wr = wid >> 1, wc = wid & 1;
  const int lr = l & 15, kg = l >> 4;

  f32x4 acc[4][4] = {};
  const float* Ax = x + (size_t)mrow * INNER;
  const bf16_t* Bb = BT + (size_t)ncol * INNER;
#pragma unroll
  for (int k0 = 0; k0 < INNER; k0 += 64) {
    stage_tile_cvt(Ax + k0, INNER, Al, tid);
    stage_tile(Bb + k0, INNER, Bl, tid);
    __syncthreads();
#pragma unroll
    for (int kk = 0; kk < 2; ++kk) {
      bf16x8 af[4], bfm[4];
#pragma unroll
      for (int f = 0; f < 4; ++f) {
        af[f]  = *(const bf16x8*)&Al[wr * 64 + f * 16 + lr][kk * 32 + kg * 8];
        bfm[f] = *(const bf16x8*)&Bl[wc * 64 + f * 16 + lr][kk * 32 + kg * 8];
      }
#pragma unroll
      for (int m = 0; m < 4; ++m)
#pragma unroll
        for (int n = 0; n < 4; ++n)
          acc[m][n] = __builtin_amdgcn_mfma_f32_16x16x32_bf16(
              af[m], bfm[n], acc[m][n], 0, 0, 0);
    }
    __syncthreads();
  }

#pragma unroll
  for (int m = 0; m < 4; ++m)
#pragma unroll
    for (int n = 0; n < 4; ++n)
#pragma unroll
      for (int j = 0; j < 4; ++j) {
        // C/D layout: col = lane&15, row = (lane>>4)*4 + reg  [m89]
        int r = mrow + wr * 64 + m * 16 + kg * 4 + j;
        int c = ncol + wc * 64 + n * 16 + lr;
        Y[(size_t)r * INNER + c] = (bf16_t)acc[m][n][j];
      }
}

// ---- Kernel 2: E = Y @ x^T * scale (+ diag mask); lower tiles fill -1e9 ----
// Round-7 verified structure. A = Y (bf16, gload_lds), B = x (fp32, cvt
// staging). XCD pin `b = bid & 7`: Y_b (1MB) + x_b (2MB) < 4MiB per-XCD L2.
// Lower-triangle blocks do the -1e9 fill so fill writes overlap compute
// blocks' stage/MFMA phases.
__global__ __launch_bounds__(256) void scores_kernel(
    const bf16_t* __restrict__ Y, const float* __restrict__ x,
    float* __restrict__ E) {
  const int bid = blockIdx.x;
  const int b = bid & 7;       // batch == XCD
  const int lid = bid >> 3;    // 0..255 tile id within batch
  const int rt = lid >> 4;     // row tile (t)
  const int ct = lid & 15;     // col tile (s)
  const int tid = threadIdx.x;
  float* Eb = E + (size_t)b * T_DIM * T_DIM;
  const int trow = rt * 128, scol = ct * 128;

  if (ct < rt) {
    // strictly below diagonal: exact -1e9 fill (512B row segments)
    const f32x4 neg = {NEGV, NEGV, NEGV, NEGV};
#pragma unroll
    for (int it = 0; it < 16; ++it) {
      int idx = it * 256 + tid;          // 0..4095 float4 slots
      int r = idx >> 5, c4 = idx & 31;
      *(f32x4*)&Eb[(size_t)(trow + r) * T_DIM + scol + c4 * 4] = neg;
    }
    return;
  }

  __shared__ bf16_t Al[128][64];
  __shared__ bf16_t Bl[128][64];
  const int l = tid & 63, wid = tid >> 6, wr = wid >> 1, wc = wid & 1;
  const int lr = l & 15, kg = l >> 4;

  f32x4 acc[4][4] = {};
  const bf16_t* Ya = Y + ((size_t)b * T_DIM + trow) * INNER;
  const float* xs = x + ((size_t)b * T_DIM + scol) * INNER;
#pragma unroll
  for (int k0 = 0; k0 < INNER; k0 += 64) {
    stage_tile(Ya + k0, INNER, Al, tid);
    stage_tile_cvt(xs + k0, INNER, Bl, tid);
    __syncthreads();   // drains vmcnt+lgkmcnt before s_barrier
#pragma unroll
    for (int kk = 0; kk < 2; ++kk) {
      bf16x8 af[4], bfm[4];
#pragma unroll
      for (int f = 0; f < 4; ++f) {
        af[f]  = *(const bf16x8*)&Al[wr * 64 + f * 16 + lr][kk * 32 + kg * 8];
        bfm[f] = *(const bf16x8*)&Bl[wc * 64 + f * 16 + lr][kk * 32 + kg * 8];
      }
#pragma unroll
      for (int m = 0; m < 4; ++m)
#pragma unroll
        for (int n = 0; n < 4; ++n)
          acc[m][n] = __builtin_amdgcn_mfma_f32_16x16x32_bf16(
              af[m], bfm[n], acc[m][n], 0, 0, 0);
    }
    __syncthreads();
  }

  const bool diag = (ct == rt);
#pragma unroll
  for (int m = 0; m < 4; ++m)
#pragma unroll
    for (int n = 0; n < 4; ++n)
#pragma unroll
      for (int j = 0; j < 4; ++j) {
        int t = trow + wr * 64 + m * 16 + kg * 4 + j;
        int s = scol + wc * 64 + n * 16 + lr;
        float v = acc[m][n][j] * SCALE;
        if (diag && s < t) v += NEGV;
        Eb[(size_t)t * T_DIM + s] = v;
      }
}

extern "C" void kernel_launch(void* const* d_in, const int* in_sizes, int n_in,
                              void* d_out, int out_size, void* d_ws,
                              size_t ws_size, hipStream_t stream) {
  const float* x  = (const float*)d_in[0];   // [8,2048,256] fp32
  const float* Wq = (const float*)d_in[1];   // [256,256] fp32
  const float* Wk = (const float*)d_in[2];   // [256,256] fp32
  float* out = (float*)d_out;

  const size_t n_x = (size_t)B_DIM * T_DIM * INNER;  // 4,194,304

  // Workspace layout (bf16): Y (8.4 MB) | BT (128 KB)
  bf16_t* Y  = (bf16_t*)d_ws;
  bf16_t* BT = Y + n_x;

  m_kernel<<<256, 256, 0, stream>>>(Wq, Wk, BT);

  dim3 g1(B_DIM * T_DIM / 128, INNER / 128);     // (128, 2) = 256 blocks
  y_kernel<<<g1, dim3(256), 0, stream>>>(x, BT, Y);

  scores_kernel<<<2048, 256, 0, stream>>>(Y, x, out);
}

// Round 13
// 57.300 us; speedup vs baseline: 1.0919x; 1.0919x over previous
//
#include <hip/hip_runtime.h>
#include <hip/hip_bf16.h>
#include <stdint.h>

// Problem constants
#define B_DIM 8
#define T_DIM 2048
#define INNER 256      // IN_DIM == HEAD_TOTAL == 256
#define NEGV (-1e9f)
#define SCALE 0.0625f  // 1/sqrt(256)

typedef __bf16 bf16_t;
typedef __bf16 bf16x4_t __attribute__((ext_vector_type(4)));
typedef __bf16 bf16x8 __attribute__((ext_vector_type(8)));
typedef float f32x4 __attribute__((ext_vector_type(4)));

// ---- async global->LDS, 16B per lane (global_load_lds_dwordx4) ----
__device__ inline void gload_lds16(const bf16_t* g, bf16_t* lds) {
  __builtin_amdgcn_global_load_lds(
      (__attribute__((address_space(1))) void*)(g),
      (__attribute__((address_space(3))) void*)(lds),
      16, 0, 0);
}

// Stage a 128x64 bf16 tile (row stride ldg elements) into lds[128][64].
// Linear LDS layout; wave-uniform LDS base + lane*16 (HW requirement).
__device__ inline void stage_tile(const bf16_t* gbase, int ldg,
                                  bf16_t (*lds)[64], int tid) {
  const int l = tid & 63;
  const int w = tid >> 6;
  const int sub = l >> 3;        // row within 8-row chunk
  const int ce = (l & 7) * 8;    // starting column element (8 bf16 = 16B)
#pragma unroll
  for (int i = 0; i < 4; ++i) {
    const int chunk = i * 4 + w;               // 0..15, uniform per wave
    const int row = chunk * 8 + sub;
    gload_lds16(gbase + (size_t)row * ldg + ce, &lds[chunk * 8][0]);
  }
}

// Stage a 128x64 tile from FP32 global into bf16 LDS (reg-staged convert),
// 256 threads. OK at proj scale (few hundred blocks); too costly in scores
// [round-12 post-mortem: lost gload_lds + 2x read bytes there].
__device__ inline void stage_tile_cvt(const float* gbase, int ldg,
                                      bf16_t (*lds)[64], int tid) {
  const int l = tid & 63;
  const int w = tid >> 6;
  const int sub = l >> 3;
  const int ce = (l & 7) * 8;
  f32x4 v[4][2];
#pragma unroll
  for (int i = 0; i < 4; ++i) {
    const int row = (i * 4 + w) * 8 + sub;
    const float* p = gbase + (size_t)row * ldg + ce;
    v[i][0] = *(const f32x4*)p;
    v[i][1] = *(const f32x4*)(p + 4);
  }
#pragma unroll
  for (int i = 0; i < 4; ++i) {
    const int row = (i * 4 + w) * 8 + sub;
    bf16x8 o;
#pragma unroll
    for (int j = 0; j < 4; ++j) {
      o[j]     = (bf16_t)v[i][0][j];
      o[4 + j] = (bf16_t)v[i][1][j];
    }
    *(bf16x8*)&lds[row][ce] = o;
  }
}

// ---- Kernel 0: BT[j][i] = sum_o Wq[o][i] * Wk[o][j]  (= M^T, bf16) ----
// e = x Wq^T Wk x^T = (x M) x^T with M = Wq^T Wk. BT is M stored [j][i] so
// the downstream GEMM (C = A B^T, operands [row][k]) consumes it directly.
__global__ __launch_bounds__(256) void m_kernel(
    const float* __restrict__ Wq, const float* __restrict__ Wk,
    bf16_t* __restrict__ BT) {
  const int j = blockIdx.x;    // 0..255
  const int i = threadIdx.x;   // 0..255
  float a0 = 0.f, a1 = 0.f, a2 = 0.f, a3 = 0.f;
#pragma unroll 8
  for (int o = 0; o < INNER; o += 4) {
    const float k0 = Wk[(size_t)(o + 0) * INNER + j];
    const float k1 = Wk[(size_t)(o + 1) * INNER + j];
    const float k2 = Wk[(size_t)(o + 2) * INNER + j];
    const float k3 = Wk[(size_t)(o + 3) * INNER + j];
    a0 += Wq[(size_t)(o + 0) * INNER + i] * k0;
    a1 += Wq[(size_t)(o + 1) * INNER + i] * k1;
    a2 += Wq[(size_t)(o + 2) * INNER + i] * k2;
    a3 += Wq[(size_t)(o + 3) * INNER + i] * k3;
  }
  BT[(size_t)j * INNER + i] = (bf16_t)((a0 + a1) + (a2 + a3));
}

// ---- Kernel 1: fused {Y = x @ M} + {xb = bf16(x)} in one dispatch ----
// Blocks [0,256): 128x128 GEMM tiles of Y (A = x fp32 cvt-staged, B = BT
// bf16 via gload_lds). Blocks [256,512): grid-stride convert x -> xb; the
// convert's pure-memory work overlaps the GEMM blocks' MFMA phases.
__global__ __launch_bounds__(256) void y_kernel(
    const float* __restrict__ x, const bf16_t* __restrict__ BT,
    bf16_t* __restrict__ Y, bf16_t* __restrict__ xb) {
  const int bid = blockIdx.x;
  const int tid = threadIdx.x;

  if (bid >= 256) {
    // ---- convert block: x (fp32) -> xb (bf16), vectorized grid-stride ----
    const int n4 = (B_DIM * T_DIM * INNER) / 4;        // 1,048,576 float4
    for (int i = (bid - 256) * 256 + tid; i < n4; i += 256 * 256) {
      f32x4 v = *(const f32x4*)&x[(size_t)i * 4];
      bf16x4_t o;
      o[0] = (bf16_t)v[0]; o[1] = (bf16_t)v[1];
      o[2] = (bf16_t)v[2]; o[3] = (bf16_t)v[3];
      *(bf16x4_t*)&xb[(size_t)i * 4] = o;
    }
    return;
  }

  // ---- GEMM block: one 128x128 tile of Y ----
  __shared__ bf16_t Al[128][64];
  __shared__ bf16_t Bl[128][64];
  const int mrow = (bid & 127) * 128;  // row in [0, B*T)
  const int ncol = (bid >> 7) * 128;   // out-feature j (0 or 128)

  const int l = tid & 63, wid = tid >> 6, wr = wid >> 1, wc = wid & 1;
  const int lr = l & 15, kg = l >> 4;

  f32x4 acc[4][4] = {};
  const float* Ax = x + (size_t)mrow * INNER;
  const bf16_t* Bb = BT + (size_t)ncol * INNER;
#pragma unroll
  for (int k0 = 0; k0 < INNER; k0 += 64) {
    stage_tile_cvt(Ax + k0, INNER, Al, tid);
    stage_tile(Bb + k0, INNER, Bl, tid);
    __syncthreads();
#pragma unroll
    for (int kk = 0; kk < 2; ++kk) {
      bf16x8 af[4], bfm[4];
#pragma unroll
      for (int f = 0; f < 4; ++f) {
        af[f]  = *(const bf16x8*)&Al[wr * 64 + f * 16 + lr][kk * 32 + kg * 8];
        bfm[f] = *(const bf16x8*)&Bl[wc * 64 + f * 16 + lr][kk * 32 + kg * 8];
      }
#pragma unroll
      for (int m = 0; m < 4; ++m)
#pragma unroll
        for (int n = 0; n < 4; ++n)
          acc[m][n] = __builtin_amdgcn_mfma_f32_16x16x32_bf16(
              af[m], bfm[n], acc[m][n], 0, 0, 0);
    }
    __syncthreads();
  }

#pragma unroll
  for (int m = 0; m < 4; ++m)
#pragma unroll
    for (int n = 0; n < 4; ++n)
#pragma unroll
      for (int j = 0; j < 4; ++j) {
        // C/D layout: col = lane&15, row = (lane>>4)*4 + reg  [m89]
        int r = mrow + wr * 64 + m * 16 + kg * 4 + j;
        int c = ncol + wc * 64 + n * 16 + lr;
        Y[(size_t)r * INNER + c] = (bf16_t)acc[m][n][j];
      }
}

// ---- Kernel 2: E = Y @ xb^T * scale (+ diag mask); lower tiles fill ----
// Byte-for-byte the round-7 (47.1us) structure: both operands bf16 via
// gload_lds, m97 single-buffered loop, batch<->XCD pin (`b = bid & 7`,
// Y_b + xb_b = 2MB fits the 4MiB per-XCD L2), lower-triangle -1e9 fill in
// the same dispatch so fill writes overlap compute blocks' stage/MFMA.
__global__ __launch_bounds__(256) void scores_kernel(
    const bf16_t* __restrict__ Y, const bf16_t* __restrict__ xb,
    float* __restrict__ E) {
  const int bid = blockIdx.x;
  const int b = bid & 7;       // batch == XCD
  const int lid = bid >> 3;    // 0..255 tile id within batch
  const int rt = lid >> 4;     // row tile (t)
  const int ct = lid & 15;     // col tile (s)
  const int tid = threadIdx.x;
  float* Eb = E + (size_t)b * T_DIM * T_DIM;
  const int trow = rt * 128, scol = ct * 128;

  if (ct < rt) {
    // strictly below diagonal: exact -1e9 fill (512B row segments)
    const f32x4 neg = {NEGV, NEGV, NEGV, NEGV};
#pragma unroll
    for (int it = 0; it < 16; ++it) {
      int idx = it * 256 + tid;          // 0..4095 float4 slots
      int r = idx >> 5, c4 = idx & 31;
      *(f32x4*)&Eb[(size_t)(trow + r) * T_DIM + scol + c4 * 4] = neg;
    }
    return;
  }

  __shared__ bf16_t Al[128][64];
  __shared__ bf16_t Bl[128][64];
  const int l = tid & 63, wid = tid >> 6, wr = wid >> 1, wc = wid & 1;
  const int lr = l & 15, kg = l >> 4;

  f32x4 acc[4][4] = {};
  const bf16_t* Ya = Y + ((size_t)b * T_DIM + trow) * INNER;
  const bf16_t* Xs = xb + ((size_t)b * T_DIM + scol) * INNER;
#pragma unroll
  for (int k0 = 0; k0 < INNER; k0 += 64) {
    stage_tile(Ya + k0, INNER, Al, tid);
    stage_tile(Xs + k0, INNER, Bl, tid);
    __syncthreads();   // compiler drains vmcnt(0) before s_barrier
#pragma unroll
    for (int kk = 0; kk < 2; ++kk) {
      bf16x8 af[4], bfm[4];
#pragma unroll
      for (int f = 0; f < 4; ++f) {
        af[f]  = *(const bf16x8*)&Al[wr * 64 + f * 16 + lr][kk * 32 + kg * 8];
        bfm[f] = *(const bf16x8*)&Bl[wc * 64 + f * 16 + lr][kk * 32 + kg * 8];
      }
#pragma unroll
      for (int m = 0; m < 4; ++m)
#pragma unroll
        for (int n = 0; n < 4; ++n)
          acc[m][n] = __builtin_amdgcn_mfma_f32_16x16x32_bf16(
              af[m], bfm[n], acc[m][n], 0, 0, 0);
    }
    __syncthreads();
  }

  const bool diag = (ct == rt);
#pragma unroll
  for (int m = 0; m < 4; ++m)
#pragma unroll
    for (int n = 0; n < 4; ++n)
#pragma unroll
      for (int j = 0; j < 4; ++j) {
        int t = trow + wr * 64 + m * 16 + kg * 4 + j;
        int s = scol + wc * 64 + n * 16 + lr;
        float v = acc[m][n][j] * SCALE;
        if (diag && s < t) v += NEGV;
        Eb[(size_t)t * T_DIM + s] = v;
      }
}

extern "C" void kernel_launch(void* const* d_in, const int* in_sizes, int n_in,
                              void* d_out, int out_size, void* d_ws,
                              size_t ws_size, hipStream_t stream) {
  const float* x  = (const float*)d_in[0];   // [8,2048,256] fp32
  const float* Wq = (const float*)d_in[1];   // [256,256] fp32
  const float* Wk = (const float*)d_in[2];   // [256,256] fp32
  float* out = (float*)d_out;

  const size_t n_x = (size_t)B_DIM * T_DIM * INNER;  // 4,194,304

  // Workspace layout (bf16): Y (8.4 MB) | xb (8.4 MB) | BT (128 KB)
  bf16_t* Y  = (bf16_t*)d_ws;
  bf16_t* xb = Y + n_x;
  bf16_t* BT = xb + n_x;

  m_kernel<<<256, 256, 0, stream>>>(Wq, Wk, BT);

  // 256 Y-GEMM blocks + 256 x->bf16 convert blocks in one dispatch
  y_kernel<<<512, 256, 0, stream>>>(x, BT, Y, xb);

  scores_kernel<<<2048, 256, 0, stream>>>(Y, xb, out);
}

// Round 14
// 50.328 us; speedup vs baseline: 1.2431x; 1.1385x over previous
//
#include <hip/hip_runtime.h>
#include <hip/hip_bf16.h>
#include <stdint.h>

// Problem constants
#define B_DIM 8
#define T_DIM 2048
#define INNER 256      // IN_DIM == HEAD_TOTAL == 256
#define NEGV (-1e9f)
#define SCALE 0.0625f  // 1/sqrt(256)

typedef __bf16 bf16_t;
typedef __bf16 bf16x8 __attribute__((ext_vector_type(8)));
typedef float f32x4 __attribute__((ext_vector_type(4)));

// ---- async global->LDS, 16B per lane (global_load_lds_dwordx4) ----
__device__ inline void gload_lds16(const bf16_t* g, bf16_t* lds) {
  __builtin_amdgcn_global_load_lds(
      (__attribute__((address_space(1))) void*)(g),
      (__attribute__((address_space(3))) void*)(lds),
      16, 0, 0);
}

// Stage a 128x64 bf16 tile (row stride ldg elements) into lds[128][64].
// Linear LDS layout; wave-uniform LDS base + lane*16 (HW requirement).
__device__ inline void stage_tile(const bf16_t* gbase, int ldg,
                                  bf16_t (*lds)[64], int tid) {
  const int l = tid & 63;
  const int w = tid >> 6;
  const int sub = l >> 3;        // row within 8-row chunk
  const int ce = (l & 7) * 8;    // starting column element (8 bf16 = 16B)
#pragma unroll
  for (int i = 0; i < 4; ++i) {
    const int chunk = i * 4 + w;               // 0..15, uniform per wave
    const int row = chunk * 8 + sub;
    gload_lds16(gbase + (size_t)row * ldg + ce, &lds[chunk * 8][0]);
  }
}

// Stage a 128x64 tile from FP32 global into bf16 LDS (reg-staged convert),
// 256 threads. Issue all 8 global loads first, then cvt + ds_write.
// [r12 lesson: fine at proj scale; never use in scores.]
__device__ inline void stage_tile_cvt(const float* gbase, int ldg,
                                      bf16_t (*lds)[64], int tid) {
  const int l = tid & 63;
  const int w = tid >> 6;
  const int sub = l >> 3;
  const int ce = (l & 7) * 8;
  f32x4 v[4][2];
#pragma unroll
  for (int i = 0; i < 4; ++i) {
    const int row = (i * 4 + w) * 8 + sub;
    const float* p = gbase + (size_t)row * ldg + ce;
    v[i][0] = *(const f32x4*)p;
    v[i][1] = *(const f32x4*)(p + 4);
  }
#pragma unroll
  for (int i = 0; i < 4; ++i) {
    const int row = (i * 4 + w) * 8 + sub;
    bf16x8 o;
#pragma unroll
    for (int j = 0; j < 4; ++j) {
      o[j]     = (bf16_t)v[i][0][j];
      o[4 + j] = (bf16_t)v[i][1][j];
    }
    *(bf16x8*)&lds[row][ce] = o;
  }
}

// 128x128 output tile GEMM, C = A * B^T, both A and Bm are [row][k] bf16.
// Single-buffered m97 structure (32KB LDS -> 5 blocks/CU). Rounds 3/8/10
// showed dbuf, wider tiles, and no-LDS all regress this shape.
template <int KDIM>
__device__ inline void gemm_bt_128(const bf16_t* A, const bf16_t* Bm, int ld,
                                   bf16_t (*Al)[64], bf16_t (*Bl)[64],
                                   f32x4 acc[4][4], int tid) {
  const int l = tid & 63;
  const int wid = tid >> 6;
  const int wr = wid >> 1, wc = wid & 1;
  const int lr = l & 15;   // fragment row (A) / col (B) lane
  const int kg = l >> 4;   // k-chunk group 0..3
#pragma unroll
  for (int k0 = 0; k0 < KDIM; k0 += 64) {
    stage_tile(A + k0, ld, Al, tid);
    stage_tile(Bm + k0, ld, Bl, tid);
    __syncthreads();   // compiler drains vmcnt(0) before s_barrier
#pragma unroll
    for (int kk = 0; kk < 2; ++kk) {
      bf16x8 af[4], bfm[4];
#pragma unroll
      for (int f = 0; f < 4; ++f) {
        af[f]  = *(const bf16x8*)&Al[wr * 64 + f * 16 + lr][kk * 32 + kg * 8];
        bfm[f] = *(const bf16x8*)&Bl[wc * 64 + f * 16 + lr][kk * 32 + kg * 8];
      }
#pragma unroll
      for (int m = 0; m < 4; ++m)
#pragma unroll
        for (int n = 0; n < 4; ++n)
          acc[m][n] = __builtin_amdgcn_mfma_f32_16x16x32_bf16(
              af[m], bfm[n], acc[m][n], 0, 0, 0);
    }
    __syncthreads();
  }
}

// ---- Kernel 1: Q = x @ Wq^T, K = x @ Wk^T, reading FP32 inputs directly ----
// fp32->bf16 conversion fused into staging (round-7 verified). 1-D grid with
// x-PANEL LOCALITY: the 4 blocks sharing one 128-row x panel (2 ncol x 2 z)
// are ADJACENT bids (mrow = bid>>2), so they run concurrently on neighboring
// CUs and the panel is fetched from HBM ~once instead of 4x.
__global__ __launch_bounds__(256) void proj_kernel(
    const float* __restrict__ x, const float* __restrict__ Wq,
    const float* __restrict__ Wk, bf16_t* __restrict__ Q,
    bf16_t* __restrict__ Kout) {
  const int bid = blockIdx.x;          // 0..511
  const int mrow = (bid >> 2) * 128;   // row in [0, B*T)
  const int ncol = (bid & 1) * 128;    // out-feature half
  const int z = (bid >> 1) & 1;        // 0 -> Q, 1 -> K

  __shared__ bf16_t Al[128][64];
  __shared__ bf16_t Bl[128][64];
  const int tid = threadIdx.x;
  const float* W = z ? Wk : Wq;
  bf16_t* O = z ? Kout : Q;

  const int l = tid & 63, wid = tid >> 6, wr = wid >> 1, wc = wid & 1;
  const int lr = l & 15, kg = l >> 4;

  f32x4 acc[4][4] = {};
  const float* Ax = x + (size_t)mrow * INNER;
  const float* Bw = W + (size_t)ncol * INNER;
#pragma unroll
  for (int k0 = 0; k0 < INNER; k0 += 64) {
    stage_tile_cvt(Ax + k0, INNER, Al, tid);
    stage_tile_cvt(Bw + k0, INNER, Bl, tid);
    __syncthreads();
#pragma unroll
    for (int kk = 0; kk < 2; ++kk) {
      bf16x8 af[4], bfm[4];
#pragma unroll
      for (int f = 0; f < 4; ++f) {
        af[f]  = *(const bf16x8*)&Al[wr * 64 + f * 16 + lr][kk * 32 + kg * 8];
        bfm[f] = *(const bf16x8*)&Bl[wc * 64 + f * 16 + lr][kk * 32 + kg * 8];
      }
#pragma unroll
      for (int m = 0; m < 4; ++m)
#pragma unroll
        for (int n = 0; n < 4; ++n)
          acc[m][n] = __builtin_amdgcn_mfma_f32_16x16x32_bf16(
              af[m], bfm[n], acc[m][n], 0, 0, 0);
    }
    __syncthreads();
  }

#pragma unroll
  for (int m = 0; m < 4; ++m)
#pragma unroll
    for (int n = 0; n < 4; ++n)
#pragma unroll
      for (int j = 0; j < 4; ++j) {
        // C/D layout: col = lane&15, row = (lane>>4)*4 + reg  [m89]
        int r = mrow + wr * 64 + m * 16 + kg * 4 + j;
        int c = ncol + wc * 64 + n * 16 + lr;
        O[(size_t)r * INNER + c] = (bf16_t)acc[m][n][j];
      }
}

// ---- Kernel 2: E = Q @ K^T * scale (+ diag mask); lower tiles fill -1e9 ----
// Round-7 verified form (47.1us). 1-D grid, 2048 blocks. XCD pin
// `b = bid & 7` (Q_b + K_b = 2 MB in the XCD's 4 MiB L2). Lower-triangle
// blocks do the -1e9 fill so fill writes overlap compute blocks' stage/MFMA.
__global__ __launch_bounds__(256) void scores_kernel(
    const bf16_t* __restrict__ Q, const bf16_t* __restrict__ Kin,
    float* __restrict__ E) {
  const int bid = blockIdx.x;
  const int b = bid & 7;       // batch == XCD
  const int lid = bid >> 3;    // 0..255 tile id within batch
  const int rt = lid >> 4;     // row tile (t)
  const int ct = lid & 15;     // col tile (s)
  const int tid = threadIdx.x;
  float* Eb = E + (size_t)b * T_DIM * T_DIM;
  const int trow = rt * 128, scol = ct * 128;

  if (ct < rt) {
    // strictly below diagonal: exact -1e9 fill (512B row segments)
    const f32x4 neg = {NEGV, NEGV, NEGV, NEGV};
#pragma unroll
    for (int it = 0; it < 16; ++it) {
      int idx = it * 256 + tid;          // 0..4095 float4 slots
      int r = idx >> 5, c4 = idx & 31;
      *(f32x4*)&Eb[(size_t)(trow + r) * T_DIM + scol + c4 * 4] = neg;
    }
    return;
  }

  __shared__ bf16_t Al[128][64];
  __shared__ bf16_t Bl[128][64];
  f32x4 acc[4][4] = {};
  const bf16_t* Qb = Q + (size_t)b * T_DIM * INNER;
  const bf16_t* Kb = Kin + (size_t)b * T_DIM * INNER;
  gemm_bt_128<INNER>(Qb + (size_t)trow * INNER, Kb + (size_t)scol * INNER,
                     INNER, Al, Bl, acc, tid);

  const int l = tid & 63, wid = tid >> 6, wr = wid >> 1, wc = wid & 1;
  const int lr = l & 15, kg = l >> 4;
  const bool diag = (ct == rt);
#pragma unroll
  for (int m = 0; m < 4; ++m)
#pragma unroll
    for (int n = 0; n < 4; ++n)
#pragma unroll
      for (int j = 0; j < 4; ++j) {
        int t = trow + wr * 64 + m * 16 + kg * 4 + j;
        int s = scol + wc * 64 + n * 16 + lr;
        float v = acc[m][n][j] * SCALE;
        if (diag && s < t) v += NEGV;
        Eb[(size_t)t * T_DIM + s] = v;
      }
}

extern "C" void kernel_launch(void* const* d_in, const int* in_sizes, int n_in,
                              void* d_out, int out_size, void* d_ws,
                              size_t ws_size, hipStream_t stream) {
  const float* x  = (const float*)d_in[0];   // [8,2048,256] fp32
  const float* Wq = (const float*)d_in[1];   // [256,256] fp32
  const float* Wk = (const float*)d_in[2];   // [256,256] fp32
  float* out = (float*)d_out;

  const size_t n_x = (size_t)B_DIM * T_DIM * INNER;  // 4,194,304

  // Workspace layout (bf16): Q | K  (16.8 MB)
  bf16_t* Q = (bf16_t*)d_ws;
  bf16_t* K = Q + n_x;

  proj_kernel<<<512, 256, 0, stream>>>(x, Wq, Wk, Q, K);

  scores_kernel<<<2048, 256, 0, stream>>>(Q, K, out);
}